// Round 1
// baseline (355.930 us; speedup 1.0000x reference)
//
#include <hip/hip_runtime.h>
#include <hip/hip_bf16.h>
#include <cstdint>

// Problem constants (CombinedContentLoss): B=4, C=256, N=64*64=4096
#define EPS1f 1e-8f
#define EPS2f 1e-5f

typedef __bf16 bf16x8 __attribute__((ext_vector_type(8)));
typedef float floatx4 __attribute__((ext_vector_type(4)));

static constexpr int Bn = 4, Cn = 256, Nn = 4096;

// workspace layout (float offsets); total ~17.2 MB — assumes ws_size >= 18 MB
static constexpr size_t OFF_ACC   = 0;                    // 4 floats: mse1, mse2
static constexpr size_t OFF_MEANX = 16;                   // 1024
static constexpr size_t OFF_MEANY = 1040;                 // 1024
static constexpr size_t OFF_XN    = 2064;                 // 16384
static constexpr size_t OFF_YN    = 18448;                // 16384
static constexpr size_t OFF_DMIN  = 34832;                // 16384
static constexpr size_t OFF_RSUM  = 51216;                // 16384
static constexpr size_t OFF_CMAX  = 67600;                // 16384
static constexpr size_t INIT_N    = 83984;
static constexpr size_t OFF_XC    = 84000;                // bf16[4*4096*256] = 2097152 floats
static constexpr size_t OFF_YC    = 84000 + 2097152;

__device__ __forceinline__ unsigned short f2bf(float f) {
    unsigned u = __float_as_uint(f);
    u += 0x7fffu + ((u >> 16) & 1u);   // round-to-nearest-even
    return (unsigned short)(u >> 16);
}

__global__ __launch_bounds__(256) void init_kernel(float* ws) {
    int i = blockIdx.x * 256 + threadIdx.x;
    if (i < (int)INIT_N) {
        float v = (i >= (int)OFF_DMIN && i < (int)(OFF_DMIN + 16384)) ? __builtin_inff() : 0.f;
        ws[i] = v;
    }
}

__global__ __launch_bounds__(256) void mse_kernel(const float4* __restrict__ a,
                                                  const float4* __restrict__ b,
                                                  int n4, float* accp) {
    float s = 0.f;
    for (int i = blockIdx.x * blockDim.x + threadIdx.x; i < n4; i += gridDim.x * blockDim.x) {
        float4 va = a[i], vb = b[i];
        float dx = va.x - vb.x, dy = va.y - vb.y, dz = va.z - vb.z, dw = va.w - vb.w;
        s += dx * dx + dy * dy + dz * dz + dw * dw;
    }
    for (int m = 1; m < 64; m <<= 1) s += __shfl_xor(s, m);
    __shared__ float red[4];
    if ((threadIdx.x & 63) == 0) red[threadIdx.x >> 6] = s;
    __syncthreads();
    if (threadIdx.x == 0) atomicAdd(accp, red[0] + red[1] + red[2] + red[3]);
}

// one block per (channel c, batch b): mean over N positions
__global__ __launch_bounds__(256) void mean_kernel(const float* __restrict__ feat,
                                                   float* __restrict__ mean) {
    int c = blockIdx.x, b = blockIdx.y;
    const float* p = feat + ((size_t)b * Cn + c) * Nn;
    float s = 0.f;
    for (int i = threadIdx.x; i < Nn; i += 256) s += p[i];
    for (int m = 1; m < 64; m <<= 1) s += __shfl_xor(s, m);
    __shared__ float red[4];
    if ((threadIdx.x & 63) == 0) red[threadIdx.x >> 6] = s;
    __syncthreads();
    if (threadIdx.x == 0) mean[b * Cn + c] = (red[0] + red[1] + red[2] + red[3]) * (1.f / (float)Nn);
}

// center per channel, write bf16 [b][n][c] (transposed), write fp32 norms per position.
// grid: (N/64, B), 256 threads = 64 positions x 4 channel-groups
__global__ __launch_bounds__(256) void center_kernel(const float* __restrict__ feat,
                                                     const float* __restrict__ mean,
                                                     unsigned short* __restrict__ outb,
                                                     float* __restrict__ norm) {
    int b = blockIdx.y, nb = blockIdx.x;
    __shared__ float mean_s[256];
    __shared__ float sq_s[256];
    int t = threadIdx.x;
    mean_s[t] = mean[b * Cn + t];
    __syncthreads();
    int pos = t & 63, cg = t >> 6;
    int n = nb * 64 + pos;
    const float* fb = feat + (size_t)b * Cn * Nn;
    unsigned short* ob = outb + ((size_t)b * Nn + n) * Cn;
    float ss = 0.f;
    for (int c0 = cg * 64; c0 < cg * 64 + 64; c0 += 8) {
        unsigned short tmp[8];
        #pragma unroll
        for (int u = 0; u < 8; ++u) {
            float v = fb[(size_t)(c0 + u) * Nn + n] - mean_s[c0 + u];
            ss += v * v;
            tmp[u] = f2bf(v);
        }
        uint4 pk;
        pk.x = (unsigned)tmp[0] | ((unsigned)tmp[1] << 16);
        pk.y = (unsigned)tmp[2] | ((unsigned)tmp[3] << 16);
        pk.z = (unsigned)tmp[4] | ((unsigned)tmp[5] << 16);
        pk.w = (unsigned)tmp[6] | ((unsigned)tmp[7] << 16);
        *(uint4*)(ob + c0) = pk;
    }
    sq_s[t] = ss;
    __syncthreads();
    if (t < 64) {
        float s = sq_s[t] + sq_s[t + 64] + sq_s[t + 128] + sq_s[t + 192];
        norm[(size_t)b * Nn + nb * 64 + t] = sqrtf(s);
    }
}

// 128x128 tile GEMM sweep; S[x,y] = sum_c Xc[x,c]*Yc[y,c] via mfma 16x16x32 bf16.
// MODE 0: dmin[x] = min_y d ; MODE 1: rsum[x] = sum_y exp(1 - d/(dmin+eps2)) ;
// MODE 2: cmax[y] = max_x exp(1 - d/(dmin+eps2)) / rsum[x]
template <int MODE>
__global__ __launch_bounds__(256) void gemm_sweep(const unsigned short* __restrict__ Xc,
                                                  const unsigned short* __restrict__ Yc,
                                                  const float* __restrict__ xn,
                                                  const float* __restrict__ yn,
                                                  float* __restrict__ dmin,
                                                  float* __restrict__ rsum,
                                                  float* __restrict__ cmax) {
    __shared__ __align__(16) unsigned short As[128 * 40];  // stride 40 pads bank conflicts to <=2-way
    __shared__ __align__(16) unsigned short Bs[128 * 40];
    __shared__ float xn_s[128], yn_s[128], aux_s[128], aux2_s[128];

    const int t = threadIdx.x;
    const int bx = blockIdx.x, by = blockIdx.y, b = blockIdx.z;
    const size_t nb = (size_t)b * Nn;

    if (t < 128) {
        xn_s[t] = xn[nb + bx * 128 + t];
        if (MODE >= 1) aux_s[t] = 1.f / (dmin[nb + bx * 128 + t] + EPS2f);
        if (MODE == 2) aux2_s[t] = 1.f / rsum[nb + bx * 128 + t];
    } else {
        yn_s[t - 128] = yn[nb + by * 128 + (t - 128)];
    }

    const unsigned short* Ag = Xc + (nb + bx * 128) * Cn;
    const unsigned short* Bg = Yc + (nb + by * 128) * Cn;

    floatx4 acc[4][4];
    #pragma unroll
    for (int i = 0; i < 4; i++)
        #pragma unroll
        for (int j = 0; j < 4; j++) acc[i][j] = (floatx4){0.f, 0.f, 0.f, 0.f};

    const int srow = t >> 2, sq = t & 3;
    const int wid = t >> 6, lane = t & 63;
    const int wm = wid >> 1, wn = wid & 1;
    const int lr = lane & 15, lq = lane >> 4;

    for (int kk = 0; kk < Cn; kk += 32) {
        __syncthreads();
        uint4 a0 = *(const uint4*)(Ag + (size_t)srow * Cn + kk + sq * 8);
        uint4 a1 = *(const uint4*)(Ag + (size_t)(srow + 64) * Cn + kk + sq * 8);
        uint4 b0 = *(const uint4*)(Bg + (size_t)srow * Cn + kk + sq * 8);
        uint4 b1 = *(const uint4*)(Bg + (size_t)(srow + 64) * Cn + kk + sq * 8);
        *(uint4*)(As + srow * 40 + sq * 8) = a0;
        *(uint4*)(As + (srow + 64) * 40 + sq * 8) = a1;
        *(uint4*)(Bs + srow * 40 + sq * 8) = b0;
        *(uint4*)(Bs + (srow + 64) * 40 + sq * 8) = b1;
        __syncthreads();
        bf16x8 af[4], bv[4];
        #pragma unroll
        for (int i = 0; i < 4; i++)
            af[i] = *(const bf16x8*)(As + (wm * 64 + i * 16 + lr) * 40 + lq * 8);
        #pragma unroll
        for (int j = 0; j < 4; j++)
            bv[j] = *(const bf16x8*)(Bs + (wn * 64 + j * 16 + lr) * 40 + lq * 8);
        #pragma unroll
        for (int i = 0; i < 4; i++)
            #pragma unroll
            for (int j = 0; j < 4; j++)
                acc[i][j] = __builtin_amdgcn_mfma_f32_16x16x32_bf16(af[i], bv[j], acc[i][j], 0, 0, 0);
    }

    // C/D layout: col = lane&15 (lr), row = (lane>>4)*4 + reg (lq*4+r)
    if (MODE == 0) {
        float rmin[16];
        #pragma unroll
        for (int k = 0; k < 16; k++) rmin[k] = __builtin_inff();
        #pragma unroll
        for (int i = 0; i < 4; i++) {
            #pragma unroll
            for (int j = 0; j < 4; j++) {
                float ynv = yn_s[wn * 64 + j * 16 + lr];
                #pragma unroll
                for (int r = 0; r < 4; r++) {
                    float xnv = xn_s[wm * 64 + i * 16 + lq * 4 + r];
                    float d = 1.f - acc[i][j][r] / (xnv * ynv + EPS1f);
                    rmin[i * 4 + r] = fminf(rmin[i * 4 + r], d);
                }
            }
        }
        #pragma unroll
        for (int m = 1; m < 16; m <<= 1)
            #pragma unroll
            for (int k = 0; k < 16; k++) rmin[k] = fminf(rmin[k], __shfl_xor(rmin[k], m));
        if (lr == 0) {
            #pragma unroll
            for (int i = 0; i < 4; i++)
                #pragma unroll
                for (int r = 0; r < 4; r++)
                    atomicMin((int*)&dmin[nb + bx * 128 + wm * 64 + i * 16 + lq * 4 + r],
                              __float_as_int(rmin[i * 4 + r]));
        }
    } else if (MODE == 1) {
        float rs[16];
        #pragma unroll
        for (int k = 0; k < 16; k++) rs[k] = 0.f;
        #pragma unroll
        for (int i = 0; i < 4; i++) {
            float xnv[4], invd[4];
            #pragma unroll
            for (int r = 0; r < 4; r++) {
                int row = wm * 64 + i * 16 + lq * 4 + r;
                xnv[r] = xn_s[row];
                invd[r] = aux_s[row];
            }
            #pragma unroll
            for (int j = 0; j < 4; j++) {
                float ynv = yn_s[wn * 64 + j * 16 + lr];
                #pragma unroll
                for (int r = 0; r < 4; r++) {
                    float d = 1.f - acc[i][j][r] / (xnv[r] * ynv + EPS1f);
                    rs[i * 4 + r] += __expf(1.f - d * invd[r]);
                }
            }
        }
        #pragma unroll
        for (int m = 1; m < 16; m <<= 1)
            #pragma unroll
            for (int k = 0; k < 16; k++) rs[k] += __shfl_xor(rs[k], m);
        if (lr == 0) {
            #pragma unroll
            for (int i = 0; i < 4; i++)
                #pragma unroll
                for (int r = 0; r < 4; r++)
                    atomicAdd(&rsum[nb + bx * 128 + wm * 64 + i * 16 + lq * 4 + r], rs[i * 4 + r]);
        }
    } else {
        float cm[4] = {0.f, 0.f, 0.f, 0.f};
        #pragma unroll
        for (int i = 0; i < 4; i++) {
            float xnv[4], invd[4], invR[4];
            #pragma unroll
            for (int r = 0; r < 4; r++) {
                int row = wm * 64 + i * 16 + lq * 4 + r;
                xnv[r] = xn_s[row];
                invd[r] = aux_s[row];
                invR[r] = aux2_s[row];
            }
            #pragma unroll
            for (int j = 0; j < 4; j++) {
                float ynv = yn_s[wn * 64 + j * 16 + lr];
                #pragma unroll
                for (int r = 0; r < 4; r++) {
                    float d = 1.f - acc[i][j][r] / (xnv[r] * ynv + EPS1f);
                    float c = __expf(1.f - d * invd[r]) * invR[r];
                    cm[j] = fmaxf(cm[j], c);
                }
            }
        }
        #pragma unroll
        for (int m = 16; m < 64; m <<= 1)
            #pragma unroll
            for (int j = 0; j < 4; j++) cm[j] = fmaxf(cm[j], __shfl_xor(cm[j], m));
        if (lq == 0) {
            #pragma unroll
            for (int j = 0; j < 4; j++)
                atomicMax((int*)&cmax[nb + by * 128 + wn * 64 + j * 16 + lr],
                          __float_as_int(cm[j]));
        }
    }
}

__global__ __launch_bounds__(256) void finalize_kernel(const float* __restrict__ cmax,
                                                       const float* __restrict__ acc,
                                                       float* __restrict__ out) {
    float s = 0.f;
    for (int i = threadIdx.x; i < Bn * Nn; i += 256) s += cmax[i];
    for (int m = 1; m < 64; m <<= 1) s += __shfl_xor(s, m);
    __shared__ float red[4];
    if ((threadIdx.x & 63) == 0) red[threadIdx.x >> 6] = s;
    __syncthreads();
    if (threadIdx.x == 0) {
        float cs = (red[0] + red[1] + red[2] + red[3]) / (float)(Bn * Nn);
        float mse1 = acc[0] * (1.f / 786432.f);
        float mse2 = acc[1] * (1.f / 4194304.f);
        out[0] = mse1 - logf(cs) + 0.02f * mse2;
    }
}

extern "C" void kernel_launch(void* const* d_in, const int* in_sizes, int n_in,
                              void* d_out, int out_size, void* d_ws, size_t ws_size,
                              hipStream_t stream) {
    const float* outputs = (const float*)d_in[0];
    const float* targets = (const float*)d_in[1];
    const float* ofeat   = (const float*)d_in[2];
    const float* tfeat   = (const float*)d_in[3];
    float* ws  = (float*)d_ws;
    float* out = (float*)d_out;

    float* acc   = ws + OFF_ACC;
    float* meanX = ws + OFF_MEANX;
    float* meanY = ws + OFF_MEANY;
    float* xn_p  = ws + OFF_XN;
    float* yn_p  = ws + OFF_YN;
    float* dmin  = ws + OFF_DMIN;
    float* rsum  = ws + OFF_RSUM;
    float* cmax  = ws + OFF_CMAX;
    unsigned short* Xc = (unsigned short*)(ws + OFF_XC);
    unsigned short* Yc = (unsigned short*)(ws + OFF_YC);

    init_kernel<<<(INIT_N + 255) / 256, 256, 0, stream>>>(ws);
    mse_kernel<<<256, 256, 0, stream>>>((const float4*)outputs, (const float4*)targets,
                                        786432 / 4, acc + 0);
    mse_kernel<<<512, 256, 0, stream>>>((const float4*)ofeat, (const float4*)tfeat,
                                        4194304 / 4, acc + 1);
    mean_kernel<<<dim3(Cn, Bn), 256, 0, stream>>>(ofeat, meanX);
    mean_kernel<<<dim3(Cn, Bn), 256, 0, stream>>>(tfeat, meanY);
    center_kernel<<<dim3(Nn / 64, Bn), 256, 0, stream>>>(ofeat, meanX, Xc, xn_p);
    center_kernel<<<dim3(Nn / 64, Bn), 256, 0, stream>>>(tfeat, meanY, Yc, yn_p);

    dim3 g(Nn / 128, Nn / 128, Bn);
    gemm_sweep<0><<<g, 256, 0, stream>>>(Xc, Yc, xn_p, yn_p, dmin, rsum, cmax);
    gemm_sweep<1><<<g, 256, 0, stream>>>(Xc, Yc, xn_p, yn_p, dmin, rsum, cmax);
    gemm_sweep<2><<<g, 256, 0, stream>>>(Xc, Yc, xn_p, yn_p, dmin, rsum, cmax);

    finalize_kernel<<<1, 256, 0, stream>>>(cmax, acc, out);
}

// Round 3
// 276.913 us; speedup vs baseline: 1.2853x; 1.2853x over previous
//
#include <hip/hip_runtime.h>
#include <hip/hip_bf16.h>
#include <cstdint>

#define EPS1f 1e-8f
#define EPS2f 1e-5f

typedef __bf16 bf16x8 __attribute__((ext_vector_type(8)));
typedef float floatx4 __attribute__((ext_vector_type(4)));
typedef _Float16 half8 __attribute__((ext_vector_type(8)));
typedef __fp16 fp16x2 __attribute__((ext_vector_type(2)));

static constexpr int Bn = 4, Cn = 256, Nn = 4096;

// workspace layout (float offsets)
static constexpr size_t OFF_ACC   = 0;        // 16
static constexpr size_t OFF_MEANX = 16;       // 1024
static constexpr size_t OFF_MEANY = 1040;     // 1024
static constexpr size_t OFF_XN    = 2064;     // 16384
static constexpr size_t OFF_YN    = 18448;    // 16384
static constexpr size_t OFF_IXN   = 34832;    // 16384
static constexpr size_t OFF_IYN   = 51216;    // 16384
static constexpr size_t OFF_DMIN  = 67600;    // 16384
static constexpr size_t OFF_RSUM  = 83984;    // 16384 (fallback only)
static constexpr size_t OFF_CMAX  = 100368;   // 16384
static constexpr size_t OFF_PACK  = 116752;   // 32768 (float2[16384])
static constexpr size_t OFF_XC    = 149520;   // bf16[4*4096*256] = 2097152 floats
static constexpr size_t OFF_YC    = 149520 + 2097152;
static constexpr size_t OFF_S     = 149520 + 2 * 2097152;          // 4343824
static constexpr size_t TOTAL_FLOATS = OFF_S + 33554432;           // S = 128 MB of halves
static constexpr size_t WS_NEEDED = TOTAL_FLOATS * 4;              // ~144.6 MB

__device__ __forceinline__ unsigned short f2bf(float f) {
    unsigned u = __float_as_uint(f);
    u += 0x7fffu + ((u >> 16) & 1u);
    return (unsigned short)(u >> 16);
}

__global__ __launch_bounds__(256) void init_kernel(float* ws) {
    int i = blockIdx.x * 256 + threadIdx.x;  // 16384 threads
    ws[OFF_DMIN + i] = __builtin_inff();
    ws[OFF_RSUM + i] = 0.f;
    ws[OFF_CMAX + i] = 0.f;
    if (i < 16) ws[OFF_ACC + i] = 0.f;
}

__global__ __launch_bounds__(256) void mse_fused(const float4* __restrict__ a1,
                                                 const float4* __restrict__ b1p, int n1,
                                                 const float4* __restrict__ a2,
                                                 const float4* __restrict__ b2p, int n2,
                                                 float* acc) {
    const float4 *A, *B; int n, base, nb; float* p;
    if (blockIdx.x < 256) { A = a1; B = b1p; n = n1; base = blockIdx.x; nb = 256; p = acc; }
    else { A = a2; B = b2p; n = n2; base = blockIdx.x - 256; nb = 512; p = acc + 1; }
    float s = 0.f;
    for (int i = base * 256 + threadIdx.x; i < n; i += nb * 256) {
        float4 va = A[i], vb = B[i];
        float dx = va.x - vb.x, dy = va.y - vb.y, dz = va.z - vb.z, dw = va.w - vb.w;
        s += dx * dx + dy * dy + dz * dz + dw * dw;
    }
    for (int m = 1; m < 64; m <<= 1) s += __shfl_xor(s, m);
    __shared__ float red[4];
    if ((threadIdx.x & 63) == 0) red[threadIdx.x >> 6] = s;
    __syncthreads();
    if (threadIdx.x == 0) atomicAdd(p, red[0] + red[1] + red[2] + red[3]);
}

__global__ __launch_bounds__(256) void mean_fused(const float* __restrict__ ofeat,
                                                  const float* __restrict__ tfeat,
                                                  float* __restrict__ meanX,
                                                  float* __restrict__ meanY) {
    int c = blockIdx.x, b = blockIdx.y, z = blockIdx.z;
    const float* feat = z ? tfeat : ofeat;
    float* mean = z ? meanY : meanX;
    const float* p = feat + ((size_t)b * Cn + c) * Nn;
    float s = 0.f;
    for (int i = threadIdx.x; i < Nn; i += 256) s += p[i];
    for (int m = 1; m < 64; m <<= 1) s += __shfl_xor(s, m);
    __shared__ float red[4];
    if ((threadIdx.x & 63) == 0) red[threadIdx.x >> 6] = s;
    __syncthreads();
    if (threadIdx.x == 0) mean[b * Cn + c] = (red[0] + red[1] + red[2] + red[3]) * (1.f / (float)Nn);
}

__global__ __launch_bounds__(256) void center_fused(const float* __restrict__ ofeat,
                                                    const float* __restrict__ tfeat,
                                                    const float* __restrict__ meanX,
                                                    const float* __restrict__ meanY,
                                                    unsigned short* __restrict__ Xc,
                                                    unsigned short* __restrict__ Yc,
                                                    float* __restrict__ xn,
                                                    float* __restrict__ yn,
                                                    float* __restrict__ ixn,
                                                    float* __restrict__ iyn) {
    int b = blockIdx.y, nb = blockIdx.x, z = blockIdx.z;
    const float* feat = z ? tfeat : ofeat;
    const float* mean = z ? meanY : meanX;
    unsigned short* outb = z ? Yc : Xc;
    float* norm = z ? yn : xn;
    float* inv  = z ? iyn : ixn;
    __shared__ float mean_s[256];
    __shared__ float sq_s[256];
    int t = threadIdx.x;
    mean_s[t] = mean[b * Cn + t];
    __syncthreads();
    int pos = t & 63, cg = t >> 6;
    int n = nb * 64 + pos;
    const float* fb = feat + (size_t)b * Cn * Nn;
    unsigned short* ob = outb + ((size_t)b * Nn + n) * Cn;
    float ss = 0.f;
    for (int c0 = cg * 64; c0 < cg * 64 + 64; c0 += 8) {
        unsigned short tmp[8];
        #pragma unroll
        for (int u = 0; u < 8; ++u) {
            float v = fb[(size_t)(c0 + u) * Nn + n] - mean_s[c0 + u];
            ss += v * v;
            tmp[u] = f2bf(v);
        }
        uint4 pk;
        pk.x = (unsigned)tmp[0] | ((unsigned)tmp[1] << 16);
        pk.y = (unsigned)tmp[2] | ((unsigned)tmp[3] << 16);
        pk.z = (unsigned)tmp[4] | ((unsigned)tmp[5] << 16);
        pk.w = (unsigned)tmp[6] | ((unsigned)tmp[7] << 16);
        *(uint4*)(ob + c0) = pk;
    }
    sq_s[t] = ss;
    __syncthreads();
    if (t < 64) {
        float s = sq_s[t] + sq_s[t + 64] + sq_s[t + 128] + sq_s[t + 192];
        float nv = sqrtf(s);
        norm[(size_t)b * Nn + nb * 64 + t] = nv;
        inv[(size_t)b * Nn + nb * 64 + t] = 1.f / nv;
    }
}

// ---------------- main path: GEMM once + store cos^T (fp16) + dmin -------------
__global__ __launch_bounds__(256) void gemm_store(const unsigned short* __restrict__ Xc,
                                                  const unsigned short* __restrict__ Yc,
                                                  const float* __restrict__ ixn,
                                                  const float* __restrict__ iyn,
                                                  float* __restrict__ dmin,
                                                  _Float16* __restrict__ S) {
    __shared__ __align__(16) unsigned short As[128 * 40];
    __shared__ __align__(16) unsigned short Bs[128 * 40];
    __shared__ float ixn_s[128], iyn_s[128];

    const int t = threadIdx.x;
    const int bx = blockIdx.x, by = blockIdx.y, b = blockIdx.z;
    const size_t nb = (size_t)b * Nn;

    if (t < 128) ixn_s[t] = ixn[nb + bx * 128 + t];
    else iyn_s[t - 128] = iyn[nb + by * 128 + (t - 128)];

    const unsigned short* Ag = Xc + (nb + bx * 128) * Cn;
    const unsigned short* Bg = Yc + (nb + by * 128) * Cn;

    floatx4 acc[4][4];
    #pragma unroll
    for (int i = 0; i < 4; i++)
        #pragma unroll
        for (int j = 0; j < 4; j++) acc[i][j] = (floatx4){0.f, 0.f, 0.f, 0.f};

    const int srow = t >> 2, sq = t & 3;
    const int wid = t >> 6, lane = t & 63;
    const int wm = wid >> 1, wn = wid & 1;
    const int lr = lane & 15, lq = lane >> 4;

    for (int kk = 0; kk < Cn; kk += 32) {
        __syncthreads();
        uint4 a0 = *(const uint4*)(Ag + (size_t)srow * Cn + kk + sq * 8);
        uint4 a1 = *(const uint4*)(Ag + (size_t)(srow + 64) * Cn + kk + sq * 8);
        uint4 b0 = *(const uint4*)(Bg + (size_t)srow * Cn + kk + sq * 8);
        uint4 b1 = *(const uint4*)(Bg + (size_t)(srow + 64) * Cn + kk + sq * 8);
        *(uint4*)(As + srow * 40 + sq * 8) = a0;
        *(uint4*)(As + (srow + 64) * 40 + sq * 8) = a1;
        *(uint4*)(Bs + srow * 40 + sq * 8) = b0;
        *(uint4*)(Bs + (srow + 64) * 40 + sq * 8) = b1;
        __syncthreads();
        bf16x8 af[4], bv[4];
        #pragma unroll
        for (int i = 0; i < 4; i++)
            af[i] = *(const bf16x8*)(As + (wm * 64 + i * 16 + lr) * 40 + lq * 8);
        #pragma unroll
        for (int j = 0; j < 4; j++)
            bv[j] = *(const bf16x8*)(Bs + (wn * 64 + j * 16 + lr) * 40 + lq * 8);
        #pragma unroll
        for (int i = 0; i < 4; i++)
            #pragma unroll
            for (int j = 0; j < 4; j++)
                acc[i][j] = __builtin_amdgcn_mfma_f32_16x16x32_bf16(af[i], bv[j], acc[i][j], 0, 0, 0);
    }

    // epilogue: cos = acc*ixn*iyn ; store S^T[b][Y][X] fp16 ; dmin[x] via min over y
    float rmin[16];
    #pragma unroll
    for (int k = 0; k < 16; k++) rmin[k] = __builtin_inff();

    float ix[16];
    #pragma unroll
    for (int i = 0; i < 4; i++)
        #pragma unroll
        for (int r = 0; r < 4; r++) ix[i * 4 + r] = ixn_s[wm * 64 + i * 16 + lq * 4 + r];

    #pragma unroll
    for (int i = 0; i < 4; i++) {
        const int Xbase = bx * 128 + wm * 64 + i * 16 + lq * 4;
        #pragma unroll
        for (int j = 0; j < 4; j++) {
            const int Y = by * 128 + wn * 64 + j * 16 + lr;
            float iy = iyn_s[wn * 64 + j * 16 + lr];
            float c0 = acc[i][j][0] * ix[i * 4 + 0] * iy;
            float c1 = acc[i][j][1] * ix[i * 4 + 1] * iy;
            float c2 = acc[i][j][2] * ix[i * 4 + 2] * iy;
            float c3 = acc[i][j][3] * ix[i * 4 + 3] * iy;
            rmin[i * 4 + 0] = fminf(rmin[i * 4 + 0], 1.f - c0);
            rmin[i * 4 + 1] = fminf(rmin[i * 4 + 1], 1.f - c1);
            rmin[i * 4 + 2] = fminf(rmin[i * 4 + 2], 1.f - c2);
            rmin[i * 4 + 3] = fminf(rmin[i * 4 + 3], 1.f - c3);
            fp16x2 p0 = __builtin_amdgcn_cvt_pkrtz(c0, c1);
            fp16x2 p1 = __builtin_amdgcn_cvt_pkrtz(c2, c3);
            float2 f2 = make_float2(__builtin_bit_cast(float, p0),
                                    __builtin_bit_cast(float, p1));
            *(float2*)(S + ((size_t)b * Nn + Y) * Nn + Xbase) = f2;
        }
    }
    #pragma unroll
    for (int m = 1; m < 16; m <<= 1)
        #pragma unroll
        for (int k = 0; k < 16; k++) rmin[k] = fminf(rmin[k], __shfl_xor(rmin[k], m));
    if (lr == 0) {
        #pragma unroll
        for (int i = 0; i < 4; i++)
            #pragma unroll
            for (int r = 0; r < 4; r++)
                atomicMin((int*)&dmin[nb + bx * 128 + wm * 64 + i * 16 + lq * 4 + r],
                          __float_as_int(rmin[i * 4 + r]));
    }
}

// B1: per-x rsum.  S^T layout: rows=y, cols=x.  Block owns 64 x's, streams all y.
__global__ __launch_bounds__(256) void b1_rsum(const _Float16* __restrict__ S,
                                               const float* __restrict__ dmin,
                                               float2* __restrict__ pack) {
    __shared__ float red[32 * 65];
    const int t = threadIdx.x;
    const int c0 = blockIdx.x * 64, b = blockIdx.y;
    const int chunk = t & 7, yg = t >> 3;
    const int xbase = c0 + chunk * 8;
    const size_t gb = (size_t)b * Nn;

    float invd[8], av[8];
    #pragma unroll
    for (int u = 0; u < 8; u++) {
        float dm = dmin[gb + xbase + u];
        invd[u] = 1.f / (dm + EPS2f);
        av[u] = 1.f - invd[u];
    }
    float s[8];
    #pragma unroll
    for (int u = 0; u < 8; u++) s[u] = 0.f;

    for (int k = 0; k < 128; k++) {
        int y = yg + 32 * k;
        half8 hv = *(const half8*)(S + (gb + y) * Nn + xbase);
        #pragma unroll
        for (int u = 0; u < 8; u++) {
            float c = (float)hv[u];
            s[u] += __expf(fmaf(c, invd[u], av[u]));
        }
    }
    #pragma unroll
    for (int u = 0; u < 8; u++) red[yg * 65 + chunk * 8 + u] = s[u];
    __syncthreads();
    if (t < 64) {
        float rs = 0.f;
        #pragma unroll 8
        for (int g = 0; g < 32; g++) rs += red[g * 65 + t];
        float dm = dmin[gb + c0 + t];
        float iv = 1.f / (dm + EPS2f);
        float gg = 1.f - iv - __logf(rs);   // exp(fma(cos,iv,gg)) = w/rsum
        pack[gb + c0 + t] = make_float2(iv, gg);
    }
}

// B2: per-y cmax = max_x exp(fma(cos, invd[x], g[x])).  Block owns 16 y's.
__global__ __launch_bounds__(256) void b2_cmax(const _Float16* __restrict__ S,
                                               const float2* __restrict__ pack,
                                               float* __restrict__ cmax) {
    // pack staged in LDS, chunk-of-8-x stride 80B (20 floats) to spread quads
    __shared__ float ps[512 * 20];
    const int t = threadIdx.x;
    const int b = blockIdx.y;
    const size_t gb = (size_t)b * Nn;
    for (int i = t; i < Nn; i += 256) {
        float2 p = pack[gb + i];
        int c = i >> 3, e = i & 7;
        ps[c * 20 + e * 2] = p.x;
        ps[c * 20 + e * 2 + 1] = p.y;
    }
    __syncthreads();

    const int lanegrp = t & 15, yloc = t >> 4;
    const int y = blockIdx.x * 16 + yloc;
    const _Float16* Sy = S + (gb + y) * Nn;

    float cm = 0.f;
    for (int k = 0; k < 32; k++) {
        int chunk = lanegrp + 16 * k;
        half8 hv = *(const half8*)(Sy + chunk * 8);
        const float* pp = &ps[chunk * 20];
        float4 p01 = *(const float4*)(pp);
        float4 p23 = *(const float4*)(pp + 4);
        float4 p45 = *(const float4*)(pp + 8);
        float4 p67 = *(const float4*)(pp + 12);
        float iv[8] = {p01.x, p01.z, p23.x, p23.z, p45.x, p45.z, p67.x, p67.z};
        float gg[8] = {p01.y, p01.w, p23.y, p23.w, p45.y, p45.w, p67.y, p67.w};
        #pragma unroll
        for (int u = 0; u < 8; u++) {
            float c = (float)hv[u];
            cm = fmaxf(cm, __expf(fmaf(c, iv[u], gg[u])));
        }
    }
    #pragma unroll
    for (int m = 1; m < 16; m <<= 1) cm = fmaxf(cm, __shfl_xor(cm, m));
    if (lanegrp == 0) cmax[gb + y] = cm;
}

// ---------------- fallback path (round-1, proven): 3 GEMM sweeps ----------------
template <int MODE>
__global__ __launch_bounds__(256) void gemm_sweep(const unsigned short* __restrict__ Xc,
                                                  const unsigned short* __restrict__ Yc,
                                                  const float* __restrict__ xn,
                                                  const float* __restrict__ yn,
                                                  float* __restrict__ dmin,
                                                  float* __restrict__ rsum,
                                                  float* __restrict__ cmax) {
    __shared__ __align__(16) unsigned short As[128 * 40];
    __shared__ __align__(16) unsigned short Bs[128 * 40];
    __shared__ float xn_s[128], yn_s[128], aux_s[128], aux2_s[128];

    const int t = threadIdx.x;
    const int bx = blockIdx.x, by = blockIdx.y, b = blockIdx.z;
    const size_t nb = (size_t)b * Nn;

    if (t < 128) {
        xn_s[t] = xn[nb + bx * 128 + t];
        if (MODE >= 1) aux_s[t] = 1.f / (dmin[nb + bx * 128 + t] + EPS2f);
        if (MODE == 2) aux2_s[t] = 1.f / rsum[nb + bx * 128 + t];
    } else {
        yn_s[t - 128] = yn[nb + by * 128 + (t - 128)];
    }

    const unsigned short* Ag = Xc + (nb + bx * 128) * Cn;
    const unsigned short* Bg = Yc + (nb + by * 128) * Cn;

    floatx4 acc[4][4];
    #pragma unroll
    for (int i = 0; i < 4; i++)
        #pragma unroll
        for (int j = 0; j < 4; j++) acc[i][j] = (floatx4){0.f, 0.f, 0.f, 0.f};

    const int srow = t >> 2, sq = t & 3;
    const int wid = t >> 6, lane = t & 63;
    const int wm = wid >> 1, wn = wid & 1;
    const int lr = lane & 15, lq = lane >> 4;

    for (int kk = 0; kk < Cn; kk += 32) {
        __syncthreads();
        uint4 a0 = *(const uint4*)(Ag + (size_t)srow * Cn + kk + sq * 8);
        uint4 a1 = *(const uint4*)(Ag + (size_t)(srow + 64) * Cn + kk + sq * 8);
        uint4 b0 = *(const uint4*)(Bg + (size_t)srow * Cn + kk + sq * 8);
        uint4 b1 = *(const uint4*)(Bg + (size_t)(srow + 64) * Cn + kk + sq * 8);
        *(uint4*)(As + srow * 40 + sq * 8) = a0;
        *(uint4*)(As + (srow + 64) * 40 + sq * 8) = a1;
        *(uint4*)(Bs + srow * 40 + sq * 8) = b0;
        *(uint4*)(Bs + (srow + 64) * 40 + sq * 8) = b1;
        __syncthreads();
        bf16x8 af[4], bv[4];
        #pragma unroll
        for (int i = 0; i < 4; i++)
            af[i] = *(const bf16x8*)(As + (wm * 64 + i * 16 + lr) * 40 + lq * 8);
        #pragma unroll
        for (int j = 0; j < 4; j++)
            bv[j] = *(const bf16x8*)(Bs + (wn * 64 + j * 16 + lr) * 40 + lq * 8);
        #pragma unroll
        for (int i = 0; i < 4; i++)
            #pragma unroll
            for (int j = 0; j < 4; j++)
                acc[i][j] = __builtin_amdgcn_mfma_f32_16x16x32_bf16(af[i], bv[j], acc[i][j], 0, 0, 0);
    }

    if (MODE == 0) {
        float rmin[16];
        #pragma unroll
        for (int k = 0; k < 16; k++) rmin[k] = __builtin_inff();
        #pragma unroll
        for (int i = 0; i < 4; i++) {
            #pragma unroll
            for (int j = 0; j < 4; j++) {
                float ynv = yn_s[wn * 64 + j * 16 + lr];
                #pragma unroll
                for (int r = 0; r < 4; r++) {
                    float xnv = xn_s[wm * 64 + i * 16 + lq * 4 + r];
                    float d = 1.f - acc[i][j][r] / (xnv * ynv + EPS1f);
                    rmin[i * 4 + r] = fminf(rmin[i * 4 + r], d);
                }
            }
        }
        #pragma unroll
        for (int m = 1; m < 16; m <<= 1)
            #pragma unroll
            for (int k = 0; k < 16; k++) rmin[k] = fminf(rmin[k], __shfl_xor(rmin[k], m));
        if (lr == 0) {
            #pragma unroll
            for (int i = 0; i < 4; i++)
                #pragma unroll
                for (int r = 0; r < 4; r++)
                    atomicMin((int*)&dmin[nb + bx * 128 + wm * 64 + i * 16 + lq * 4 + r],
                              __float_as_int(rmin[i * 4 + r]));
        }
    } else if (MODE == 1) {
        float rs[16];
        #pragma unroll
        for (int k = 0; k < 16; k++) rs[k] = 0.f;
        #pragma unroll
        for (int i = 0; i < 4; i++) {
            float xnv[4], invd[4];
            #pragma unroll
            for (int r = 0; r < 4; r++) {
                int row = wm * 64 + i * 16 + lq * 4 + r;
                xnv[r] = xn_s[row];
                invd[r] = aux_s[row];
            }
            #pragma unroll
            for (int j = 0; j < 4; j++) {
                float ynv = yn_s[wn * 64 + j * 16 + lr];
                #pragma unroll
                for (int r = 0; r < 4; r++) {
                    float d = 1.f - acc[i][j][r] / (xnv[r] * ynv + EPS1f);
                    rs[i * 4 + r] += __expf(1.f - d * invd[r]);
                }
            }
        }
        #pragma unroll
        for (int m = 1; m < 16; m <<= 1)
            #pragma unroll
            for (int k = 0; k < 16; k++) rs[k] += __shfl_xor(rs[k], m);
        if (lr == 0) {
            #pragma unroll
            for (int i = 0; i < 4; i++)
                #pragma unroll
                for (int r = 0; r < 4; r++)
                    atomicAdd(&rsum[nb + bx * 128 + wm * 64 + i * 16 + lq * 4 + r], rs[i * 4 + r]);
        }
    } else {
        float cm[4] = {0.f, 0.f, 0.f, 0.f};
        #pragma unroll
        for (int i = 0; i < 4; i++) {
            float xnv[4], invd[4], invR[4];
            #pragma unroll
            for (int r = 0; r < 4; r++) {
                int row = wm * 64 + i * 16 + lq * 4 + r;
                xnv[r] = xn_s[row];
                invd[r] = aux_s[row];
                invR[r] = aux2_s[row];
            }
            #pragma unroll
            for (int j = 0; j < 4; j++) {
                float ynv = yn_s[wn * 64 + j * 16 + lr];
                #pragma unroll
                for (int r = 0; r < 4; r++) {
                    float d = 1.f - acc[i][j][r] / (xnv[r] * ynv + EPS1f);
                    float c = __expf(1.f - d * invd[r]) * invR[r];
                    cm[j] = fmaxf(cm[j], c);
                }
            }
        }
        #pragma unroll
        for (int m = 16; m < 64; m <<= 1)
            #pragma unroll
            for (int j = 0; j < 4; j++) cm[j] = fmaxf(cm[j], __shfl_xor(cm[j], m));
        if (lq == 0) {
            #pragma unroll
            for (int j = 0; j < 4; j++)
                atomicMax((int*)&cmax[nb + by * 128 + wn * 64 + j * 16 + lr],
                          __float_as_int(cm[j]));
        }
    }
}

__global__ __launch_bounds__(256) void finalize_kernel(const float* __restrict__ cmax,
                                                       const float* __restrict__ acc,
                                                       float* __restrict__ out) {
    float s = 0.f;
    for (int i = threadIdx.x; i < Bn * Nn; i += 256) s += cmax[i];
    for (int m = 1; m < 64; m <<= 1) s += __shfl_xor(s, m);
    __shared__ float red[4];
    if ((threadIdx.x & 63) == 0) red[threadIdx.x >> 6] = s;
    __syncthreads();
    if (threadIdx.x == 0) {
        float cs = (red[0] + red[1] + red[2] + red[3]) / (float)(Bn * Nn);
        float mse1 = acc[0] * (1.f / 786432.f);
        float mse2 = acc[1] * (1.f / 4194304.f);
        out[0] = mse1 - logf(cs) + 0.02f * mse2;
    }
}

extern "C" void kernel_launch(void* const* d_in, const int* in_sizes, int n_in,
                              void* d_out, int out_size, void* d_ws, size_t ws_size,
                              hipStream_t stream) {
    const float* outputs = (const float*)d_in[0];
    const float* targets = (const float*)d_in[1];
    const float* ofeat   = (const float*)d_in[2];
    const float* tfeat   = (const float*)d_in[3];
    float* ws  = (float*)d_ws;
    float* out = (float*)d_out;

    float* acc   = ws + OFF_ACC;
    float* meanX = ws + OFF_MEANX;
    float* meanY = ws + OFF_MEANY;
    float* xn_p  = ws + OFF_XN;
    float* yn_p  = ws + OFF_YN;
    float* ixn_p = ws + OFF_IXN;
    float* iyn_p = ws + OFF_IYN;
    float* dmin  = ws + OFF_DMIN;
    float* rsum  = ws + OFF_RSUM;
    float* cmax  = ws + OFF_CMAX;
    float2* pack = (float2*)(ws + OFF_PACK);
    unsigned short* Xc = (unsigned short*)(ws + OFF_XC);
    unsigned short* Yc = (unsigned short*)(ws + OFF_YC);
    _Float16* S = (_Float16*)(ws + OFF_S);

    init_kernel<<<64, 256, 0, stream>>>(ws);
    mse_fused<<<768, 256, 0, stream>>>((const float4*)outputs, (const float4*)targets, 196608,
                                       (const float4*)ofeat, (const float4*)tfeat, 1048576, acc);
    mean_fused<<<dim3(Cn, Bn, 2), 256, 0, stream>>>(ofeat, tfeat, meanX, meanY);
    center_fused<<<dim3(Nn / 64, Bn, 2), 256, 0, stream>>>(ofeat, tfeat, meanX, meanY,
                                                           Xc, Yc, xn_p, yn_p, ixn_p, iyn_p);

    if (ws_size >= WS_NEEDED) {
        dim3 g(Nn / 128, Nn / 128, Bn);
        gemm_store<<<g, 256, 0, stream>>>(Xc, Yc, ixn_p, iyn_p, dmin, S);
        b1_rsum<<<dim3(64, Bn), 256, 0, stream>>>(S, dmin, pack);
        b2_cmax<<<dim3(Nn / 16, Bn), 256, 0, stream>>>(S, pack, cmax);
    } else {
        dim3 g(Nn / 128, Nn / 128, Bn);
        gemm_sweep<0><<<g, 256, 0, stream>>>(Xc, Yc, xn_p, yn_p, dmin, rsum, cmax);
        gemm_sweep<1><<<g, 256, 0, stream>>>(Xc, Yc, xn_p, yn_p, dmin, rsum, cmax);
        gemm_sweep<2><<<g, 256, 0, stream>>>(Xc, Yc, xn_p, yn_p, dmin, rsum, cmax);
    }
    finalize_kernel<<<1, 256, 0, stream>>>(cmax, acc, out);
}